// Round 7
// baseline (156.392 us; speedup 1.0000x reference)
//
#include <hip/hip_runtime.h>

#define BB 4
#define NI 16
#define CC 3
#define HH 256
#define WW 256
#define HWSZ (HH * WW)

#define TROWS 26           // staged source-row cap (incl. +1 bottom tap row)
#define TSTR  134          // LDS row stride (floats); 134%32=6 de-banks rows

// float2 with 4-byte alignment promise (tap pairs are dword-aligned).
typedef float f2v __attribute__((ext_vector_type(2)));
typedef f2v f2u __attribute__((aligned(4)));

__device__ __forceinline__ f2v ld2(const float* __restrict__ p) {
    return *reinterpret_cast<const f2u*>(p);
}

// ---------------------------------------------------------------------------
// Per-instance scalars (uniform id -> scalar loads).
// coef = instance_valid * (mode in {0,2,4} ? 1 : mode==3 ? alpha : 0).
// ---------------------------------------------------------------------------
__device__ __forceinline__ float inst_params(
    const float* __restrict__ ml, const float* __restrict__ tp,
    const float* __restrict__ al, const float* __restrict__ iv,
    int id, float th[6]) {
    float best = ml[id * 5];
    int bid = 0;
#pragma unroll
    for (int k = 1; k < 5; ++k) {
        float v = ml[id * 5 + k];
        if (v > best) { best = v; bid = k; }   // strict >: first max, like jnp.argmax
    }
    float coef = (bid == 0 || bid == 2 || bid == 4) ? 1.0f
               : (bid == 3 ? al[id] : 0.0f);
    coef *= iv[id];
#pragma unroll
    for (int k = 0; k < 6; ++k) th[k] = tp[id * 6 + k];
    return coef;
}

// ---------------------------------------------------------------------------
// Pair-based sampler (R3-proven): x1=x0+1, y1=y0+1, so the 4 taps are a 2x2
// block based at (clamp(y0,0,H-2), clamp(x0,0,W-2)); when a clamp shifts the
// base, the corresponding weight pair swaps. OOB weights are zeroed, so the
// algebra is exact. Returns base coords + weights; caller picks LDS/global.
// ---------------------------------------------------------------------------
struct Samp {
    int bx, by;
    float wxA, wxB;        // x weights for columns bx, bx+1
    float wyA, wyB;        // y weights for rows by, by+1 (coef folded in)
};

__device__ __forceinline__ Samp make_samp(const float th[6], float coef, int p) {
    const int h = p >> 8, w = p & (WW - 1);
    const float xs = (2 * w + 1) * (1.0f / WW) - 1.0f;
    const float ys = (2 * h + 1) * (1.0f / HH) - 1.0f;
    const float gx = th[0] * xs + th[1] * ys + th[2];
    const float gy = th[3] * xs + th[4] * ys + th[5];
    const float ix = gx * (0.5f * WW) + (0.5f * WW - 0.5f);
    const float iy = gy * (0.5f * HH) + (0.5f * HH - 0.5f);
    const float x0f = floorf(ix), y0f = floorf(iy);
    const float wx1 = ix - x0f, wy1 = iy - y0f;
    const float wx0 = 1.0f - wx1, wy0 = 1.0f - wy1;
    const int x0 = (int)x0f, y0 = (int)y0f;
    const int x1 = x0 + 1, y1 = y0 + 1;
    const float wx0v = ((unsigned)x0 < (unsigned)WW) ? wx0 : 0.0f;
    const float wx1v = ((unsigned)x1 < (unsigned)WW) ? wx1 : 0.0f;
    const float wy0v = ((unsigned)y0 < (unsigned)HH) ? (coef * wy0) : 0.0f;
    const float wy1v = ((unsigned)y1 < (unsigned)HH) ? (coef * wy1) : 0.0f;
    const int bx = min(max(x0, 0), WW - 2);
    const int by = min(max(y0, 0), HH - 2);
    const bool sx = (x0 != bx);
    const bool sy = (y0 != by);
    Samp s;
    s.wxA = sx ? wx1v : wx0v;  s.wxB = sx ? wx0v : wx1v;
    s.wyA = sy ? wy1v : wy0v;  s.wyB = sy ? wy0v : wy1v;
    s.bx = bx; s.by = by;
    return s;
}

__device__ __forceinline__ float lerp22(const f2v a, const f2v b, const Samp& s) {
    return s.wyA * (s.wxA * a.x + s.wxB * a.y)
         + s.wyB * (s.wxA * b.x + s.wxB * b.y);
}

// ---------------------------------------------------------------------------
// Fused kernel, LDS-STAGED gathers.
//
// Evidence: R3 (gathers/2 -> -13%), R4 (waves x2 -> null), R5 (L2 affinity,
// FETCH/2.4 -> null), R6 (L1 tiling -> null). No counter saturated; the
// binder is the scattered-VMEM path: each wave-gather costs ~12-16 TA/TCP
// line passes (64 lanes smeared over ~7 source rows) at every cache level.
//
// Fix: per (block, instance), stage the block's source bbox into LDS with
// COALESCED row loads (8B/lane contiguous: ~4 line passes per instruction,
// ~4x fewer instructions), then tap from LDS (banked gather engine, no line
// serialization). Bbox is block-uniform from theta at the 4 patch corners
// (affine -> extremes at corners): typically ~16 rows x ~75 cols. Caps:
// TROWS=26 rows, 128 cols (27.9 KB -> 4 blocks/CU). Overflow (rare, ~2% of
// instances) takes the old global-gather path; branch is block-uniform so
// barriers stay legal.
//
// Keeps R6 decode: f&7 -> XCD slot (batch, yhalf); f>>3&1 -> plane team zz
// (0: g{0,1}; 1: {g2, mask}); f>>4 -> 64x8 patch. NT stores, same epilogue.
// ---------------------------------------------------------------------------
__global__ __launch_bounds__(512) void fused_k(
    const float* __restrict__ g0,
    const float* __restrict__ m0,
    const float* __restrict__ ml,
    const float* __restrict__ tp,
    const float* __restrict__ al,
    const float* __restrict__ iv,
    const float* __restrict__ i_bg,
    float* __restrict__ out_gpi,
    float* __restrict__ out_mpi,
    float* __restrict__ out_gmid,
    float* __restrict__ out_mmid,
    float* __restrict__ out_ibase) {
    __shared__ float tileA[TROWS * TSTR];
    __shared__ float tileB[TROWS * TSTR];

    const int f     = blockIdx.x;          // 0..1023
    const int slot  = f & 7;               // target XCD under round-robin
    const int b     = slot >> 1;           // batch
    const int yhalf = slot & 1;            // vertical half
    const int zz    = (f >> 3) & 1;        // plane team
    const int patch = f >> 4;              // 0..63
    const int wv    = threadIdx.x >> 6;    // wave = patch row 0..7
    const int ln    = threadIdx.x & 63;    // lane = patch col 0..63
    const int px0   = (patch & 3) * 64;
    const int py0   = yhalf * 128 + (patch >> 2) * 8;
    const int p     = (py0 + wv) * WW + px0 + ln;      // pixel

    const size_t offA = zz ? (size_t)(2 * HWSZ) : 0;

    // patch-corner normalized coords (block-uniform)
    const float xsL = (2 * px0 + 1) * (1.0f / WW) - 1.0f;
    const float xsR = (2 * (px0 + 63) + 1) * (1.0f / WW) - 1.0f;
    const float ysT = (2 * py0 + 1) * (1.0f / HH) - 1.0f;
    const float ysB = (2 * (py0 + 7) + 1) * (1.0f / HH) - 1.0f;

    float sA = 0.f, sB = 0.f;

#pragma unroll 1
    for (int ii = 0; ii < NI; ++ii) {
        const int id = b * NI + ii;
        float th[6];
        const float coef = inst_params(ml, tp, al, iv, id, th);

        float vA = 0.f, vB = 0.f;
        if (coef != 0.0f) {                            // block-uniform
            const Samp s = make_samp(th, coef, p);
            const float* gsrcA = g0 + (size_t)id * CC * HWSZ + offA;
            const float* gsrcB = zz ? (m0 + (size_t)id * HWSZ)
                                    : (g0 + (size_t)id * CC * HWSZ + HWSZ);

            // --- block-uniform bbox from the 4 patch corners ---
            const float ixTL = (th[0] * xsL + th[1] * ysT + th[2]) * (0.5f * WW) + (0.5f * WW - 0.5f);
            const float ixTR = (th[0] * xsR + th[1] * ysT + th[2]) * (0.5f * WW) + (0.5f * WW - 0.5f);
            const float ixBL = (th[0] * xsL + th[1] * ysB + th[2]) * (0.5f * WW) + (0.5f * WW - 0.5f);
            const float ixBR = (th[0] * xsR + th[1] * ysB + th[2]) * (0.5f * WW) + (0.5f * WW - 0.5f);
            const float iyTL = (th[3] * xsL + th[4] * ysT + th[5]) * (0.5f * HH) + (0.5f * HH - 0.5f);
            const float iyTR = (th[3] * xsR + th[4] * ysT + th[5]) * (0.5f * HH) + (0.5f * HH - 0.5f);
            const float iyBL = (th[3] * xsL + th[4] * ysB + th[5]) * (0.5f * HH) + (0.5f * HH - 0.5f);
            const float iyBR = (th[3] * xsR + th[4] * ysB + th[5]) * (0.5f * HH) + (0.5f * HH - 0.5f);
            const int x0mn = (int)floorf(fminf(fminf(ixTL, ixTR), fminf(ixBL, ixBR)));
            const int x0mx = (int)floorf(fmaxf(fmaxf(ixTL, ixTR), fmaxf(ixBL, ixBR)));
            const int y0mn = (int)floorf(fminf(fminf(iyTL, iyTR), fminf(iyBL, iyBR)));
            const int y0mx = (int)floorf(fmaxf(fmaxf(iyTL, iyTR), fmaxf(iyBL, iyBR)));
            const int bxmn = min(max(x0mn, 0), WW - 2);
            const int bxmx = min(max(x0mx, 0), WW - 2);
            const int bymn = min(max(y0mn, 0), HH - 2);
            const int bymx = min(max(y0mx, 0), HH - 2);
            const int c0    = bxmn & ~1;               // even: 8B-aligned staging
            const int wlen  = bxmx + 2 - c0;           // cols staged
            const int r0    = bymn;
            const int nrows = bymx + 2 - r0;           // rows staged (incl. +1)

            if (nrows <= TROWS && wlen <= 128) {       // block-uniform branch
                __syncthreads();                       // prev instance's reads done
                for (int r = wv; r < nrows; r += 8) {
                    const int gr = r0 + r;
                    const int c  = c0 + 2 * ln;
                    if (c <= WW - 2) {                 // stays inside the row
                        const f2v a = ld2(gsrcA + gr * WW + c);
                        const f2v q = ld2(gsrcB + gr * WW + c);
                        *(f2u*)&tileA[r * TSTR + 2 * ln] = a;
                        *(f2u*)&tileB[r * TSTR + 2 * ln] = q;
                    }
                }
                __syncthreads();                       // tile visible
                const int li = (s.by - r0) * TSTR + (s.bx - c0);
                vA = lerp22(*(const f2u*)&tileA[li],
                            *(const f2u*)&tileA[li + TSTR], s);
                vB = lerp22(*(const f2u*)&tileB[li],
                            *(const f2u*)&tileB[li + TSTR], s);
            } else {                                   // rare: global gathers
                const int oA = s.by * WW + s.bx, oB = oA + WW;
                vA = lerp22(ld2(gsrcA + oA), ld2(gsrcA + oB), s);
                vB = lerp22(ld2(gsrcB + oA), ld2(gsrcB + oB), s);
            }
        }

        float* gp = out_gpi + (size_t)id * CC * HWSZ + p;
        float* dstA = gp + offA;
        float* dstB = zz ? (out_mpi + (size_t)id * HWSZ + p) : (gp + HWSZ);
        __builtin_nontemporal_store(vA, dstA);
        __builtin_nontemporal_store(vB, dstB);

        sA += vA; sB += vB;
    }

    const size_t ob = (size_t)b * CC * HWSZ + p;
    if (zz == 0) {
        out_gmid[ob]            = sA;
        out_gmid[ob + HWSZ]     = sB;
        out_ibase[ob]           = sA + i_bg[ob];
        out_ibase[ob + HWSZ]    = sB + i_bg[ob + HWSZ];
    } else {
        out_gmid[ob + 2 * HWSZ]  = sA;
        out_ibase[ob + 2 * HWSZ] = sA + i_bg[ob + 2 * HWSZ];
        out_mmid[(size_t)b * HWSZ + p] = fminf(fmaxf(sB, 0.f), 1.f);
    }
}

extern "C" void kernel_launch(void* const* d_in, const int* in_sizes, int n_in,
                              void* d_out, int out_size, void* d_ws, size_t ws_size,
                              hipStream_t stream) {
    const float* g0          = (const float*)d_in[0];
    const float* m0          = (const float*)d_in[1];
    const float* mode_logits = (const float*)d_in[2];
    const float* tp          = (const float*)d_in[3];
    const float* alpha       = (const float*)d_in[4];
    const float* iv          = (const float*)d_in[5];
    const float* i_bg        = (const float*)d_in[6];

    float* out       = (float*)d_out;
    float* out_gpi   = out;                                        // [B,NI,C,H,W]
    float* out_mpi   = out_gpi  + (size_t)BB * NI * CC * HWSZ;     // [B,NI,1,H,W]
    float* out_gmid  = out_mpi  + (size_t)BB * NI * HWSZ;          // [B,C,H,W]
    float* out_mmid  = out_gmid + (size_t)BB * CC * HWSZ;          // [B,1,H,W]
    float* out_ibase = out_mmid + (size_t)BB * HWSZ;               // [B,C,H,W]

    fused_k<<<dim3(1024), 512, 0, stream>>>(g0, m0, mode_logits, tp, alpha, iv,
                                            i_bg, out_gpi, out_mpi,
                                            out_gmid, out_mmid, out_ibase);
}

// Round 8
// 151.174 us; speedup vs baseline: 1.0345x; 1.0345x over previous
//
#include <hip/hip_runtime.h>

#define BB 4
#define NI 16
#define CC 3
#define HH 256
#define WW 256
#define HWSZ (HH * WW)

// float2 with 4-byte alignment promise: bilinear tap pairs are only
// dword-aligned. Backend emits unaligned-capable dwordx2 (or splits legally).
typedef float f2v __attribute__((ext_vector_type(2)));
typedef f2v f2u __attribute__((aligned(4)));

__device__ __forceinline__ f2v ld2(const float* __restrict__ p) {
    return *reinterpret_cast<const f2u*>(p);
}

// ---------------------------------------------------------------------------
// Per-instance scalars (uniform id -> scalar loads).
// coef = instance_valid * (mode in {0,2,4} ? 1 : mode==3 ? alpha : 0).
// ---------------------------------------------------------------------------
__device__ __forceinline__ float inst_params(
    const float* __restrict__ ml, const float* __restrict__ tp,
    const float* __restrict__ al, const float* __restrict__ iv,
    int id, float th[6]) {
    float best = ml[id * 5];
    int bid = 0;
#pragma unroll
    for (int k = 1; k < 5; ++k) {
        float v = ml[id * 5 + k];
        if (v > best) { best = v; bid = k; }   // strict >: first max, like jnp.argmax
    }
    float coef = (bid == 0 || bid == 2 || bid == 4) ? 1.0f
               : (bid == 3 ? al[id] : 0.0f);
    coef *= iv[id];
#pragma unroll
    for (int k = 0; k < 6; ++k) th[k] = tp[id * 6 + k];
    return coef;
}

// ---------------------------------------------------------------------------
// Pair-based sampler: x1 = x0+1 and y1 = y0+1, so each (row, plane) tap pair
// is one float2 gather based at bx = clamp(x0, 0, W-2). When the clamp shifts
// the base, the x-weights swap columns; OOB weights are already zeroed, so
// the algebra stays exact. Same for the row pair.
//
// Session evidence (R1-R7): this structure at 46.4 us is the measured floor.
// Binder is TA/TCP line-pass throughput (footprint-determined): occupancy x2
// (R4), XCD L2 affinity (R5, FETCH 49->21 MB), L1 tiling (R6), and LDS
// staging (R7) were all null; gather-pairing (R3) gave the last real win.
// ---------------------------------------------------------------------------
struct Samp {
    int oA, oB;            // row-pair base offsets (column bx)
    float wxA, wxB;        // x weights for columns bx, bx+1
    float wyA, wyB;        // y weights for rows by, by+1 (coef folded in)
};

__device__ __forceinline__ Samp make_samp(const float th[6], float coef, int p) {
    const int h = p >> 8, w = p & (WW - 1);
    const float xs = (2 * w + 1) * (1.0f / WW) - 1.0f;
    const float ys = (2 * h + 1) * (1.0f / HH) - 1.0f;
    const float gx = th[0] * xs + th[1] * ys + th[2];
    const float gy = th[3] * xs + th[4] * ys + th[5];
    const float ix = gx * (0.5f * WW) + (0.5f * WW - 0.5f);
    const float iy = gy * (0.5f * HH) + (0.5f * HH - 0.5f);
    const float x0f = floorf(ix), y0f = floorf(iy);
    const float wx1 = ix - x0f, wy1 = iy - y0f;
    const float wx0 = 1.0f - wx1, wy0 = 1.0f - wy1;
    const int x0 = (int)x0f, y0 = (int)y0f;
    const int x1 = x0 + 1, y1 = y0 + 1;
    // validity-masked weights (zero outside the source image)
    const float wx0v = ((unsigned)x0 < (unsigned)WW) ? wx0 : 0.0f;
    const float wx1v = ((unsigned)x1 < (unsigned)WW) ? wx1 : 0.0f;
    const float wy0v = ((unsigned)y0 < (unsigned)HH) ? (coef * wy0) : 0.0f;
    const float wy1v = ((unsigned)y1 < (unsigned)HH) ? (coef * wy1) : 0.0f;
    // pair bases; weight-swap when the clamp shifted the base
    const int bx = min(max(x0, 0), WW - 2);
    const int by = min(max(y0, 0), HH - 2);
    const bool sx = (x0 != bx);
    const bool sy = (y0 != by);
    Samp s;
    s.wxA = sx ? wx1v : wx0v;  s.wxB = sx ? wx0v : wx1v;
    s.wyA = sy ? wy1v : wy0v;  s.wyB = sy ? wy0v : wy1v;
    s.oA = by * WW + bx;
    s.oB = s.oA + WW;
    return s;
}

__device__ __forceinline__ float bilerp(const float* __restrict__ src, const Samp& s) {
    const f2v a = ld2(src + s.oA);
    const f2v b = ld2(src + s.oB);
    return s.wyA * (s.wxA * a.x + s.wxB * a.y)
         + s.wyB * (s.wxA * b.x + s.wxB * b.y);
}

// ---------------------------------------------------------------------------
// Fused kernel (best measured: 46.4 us, dur_us 150.5): one thread owns one
// pixel across all 16 instances; instance sum in registers; gpi/mpi written
// once (nontemporal), never re-read. Rolled loop + coef-skip branch keep all
// blocks in instance-lockstep (L2-friendly) and skip inactive instances.
// ---------------------------------------------------------------------------
__global__ __launch_bounds__(512) void fused_k(
    const float* __restrict__ g0,
    const float* __restrict__ m0,
    const float* __restrict__ ml,
    const float* __restrict__ tp,
    const float* __restrict__ al,
    const float* __restrict__ iv,
    const float* __restrict__ i_bg,
    float* __restrict__ out_gpi,
    float* __restrict__ out_mpi,
    float* __restrict__ out_gmid,
    float* __restrict__ out_mmid,
    float* __restrict__ out_ibase) {
    const int b = blockIdx.y;                          // 0..3
    const int p = blockIdx.x * 512 + threadIdx.x;      // pixel in [0, HWSZ)

    float s0 = 0.f, s1 = 0.f, s2 = 0.f, sm = 0.f;

#pragma unroll 2
    for (int ii = 0; ii < NI; ++ii) {
        const int id = b * NI + ii;
        float th[6];
        const float coef = inst_params(ml, tp, al, iv, id, th);

        float v0 = 0.f, v1 = 0.f, v2 = 0.f, vm = 0.f;
        if (coef != 0.0f) {                            // block-uniform branch
            const Samp s = make_samp(th, coef, p);
            const float* gsrc = g0 + (size_t)id * CC * HWSZ;
            const float* msrc = m0 + (size_t)id * HWSZ;
            v0 = bilerp(gsrc, s);
            v1 = bilerp(gsrc + HWSZ, s);
            v2 = bilerp(gsrc + 2 * HWSZ, s);
            vm = bilerp(msrc, s);
        }

        float* gp = out_gpi + (size_t)id * CC * HWSZ + p;
        __builtin_nontemporal_store(v0, gp);
        __builtin_nontemporal_store(v1, gp + HWSZ);
        __builtin_nontemporal_store(v2, gp + 2 * HWSZ);
        __builtin_nontemporal_store(vm, out_mpi + (size_t)id * HWSZ + p);

        s0 += v0; s1 += v1; s2 += v2; sm += vm;
    }

    const size_t ob = (size_t)b * CC * HWSZ + p;
    out_gmid[ob]             = s0;
    out_gmid[ob + HWSZ]      = s1;
    out_gmid[ob + 2 * HWSZ]  = s2;
    out_ibase[ob]            = s0 + i_bg[ob];
    out_ibase[ob + HWSZ]     = s1 + i_bg[ob + HWSZ];
    out_ibase[ob + 2 * HWSZ] = s2 + i_bg[ob + 2 * HWSZ];
    out_mmid[(size_t)b * HWSZ + p] = fminf(fmaxf(sm, 0.f), 1.f);
}

extern "C" void kernel_launch(void* const* d_in, const int* in_sizes, int n_in,
                              void* d_out, int out_size, void* d_ws, size_t ws_size,
                              hipStream_t stream) {
    const float* g0          = (const float*)d_in[0];
    const float* m0          = (const float*)d_in[1];
    const float* mode_logits = (const float*)d_in[2];
    const float* tp          = (const float*)d_in[3];
    const float* alpha       = (const float*)d_in[4];
    const float* iv          = (const float*)d_in[5];
    const float* i_bg        = (const float*)d_in[6];

    float* out       = (float*)d_out;
    float* out_gpi   = out;                                        // [B,NI,C,H,W]
    float* out_mpi   = out_gpi  + (size_t)BB * NI * CC * HWSZ;     // [B,NI,1,H,W]
    float* out_gmid  = out_mpi  + (size_t)BB * NI * HWSZ;          // [B,C,H,W]
    float* out_mmid  = out_gmid + (size_t)BB * CC * HWSZ;          // [B,1,H,W]
    float* out_ibase = out_mmid + (size_t)BB * HWSZ;               // [B,C,H,W]

    dim3 grid(HWSZ / 512, BB);                                     // 128 x 4
    fused_k<<<grid, 512, 0, stream>>>(g0, m0, mode_logits, tp, alpha, iv, i_bg,
                                      out_gpi, out_mpi,
                                      out_gmid, out_mmid, out_ibase);
}